// Round 4
// baseline (76.213 us; speedup 1.0000x reference)
//
#include <hip/hip_runtime.h>
#include <math.h>
#include <stdint.h>

// PedestrianDetector v8: 1KB-contiguous DRAM bursts + full occupancy.
//
// All prior variants (v4-v7, all 40us) shared two untested properties:
// 256B-per-row read granularity (16K interleaved streams machine-wide ->
// DRAM row-buffer thrash) and 16 waves/CU. v8 changes both:
//   - 512 blocks x 1024 threads, 32 rows/block -> 2 blocks/CU, 32 waves/CU
//     (100% occupancy), two independent barrier domains per CU.
//   - buffer = 32 rows x 256 d = 32KB, double-buffered (64KB static LDS, under
//     the 64KB static limit). Each global_load_lds dwordx4 instruction fetches
//     ONE FULL 1KB contiguous row-span (16 sequential 64B lines) -> 4x better
//     DRAM row-buffer locality density than v6's 256B chunks.
//   - scalar-W path preserved: d is wave-uniform; lanes 0..31 = rows with
//     accumulators j=0..7, lanes 32..63 = same rows with j=8..14 (half-wave
//     j-split; W stays in SGPRs, ds_read broadcasts f to both halves).
//   - counted vmcnt(2): next buffer's 2 stage-instrs/wave stay in flight
//     across barriers (32KB/block outstanding during compute).
// Reduce + epilogue logic identical to harness-verified v4/v6 (adapted to 32
// rows): stride-15 partials, biased sums alias LDS behind barriers, stable
// top-3, packed out.

#define DCOLS 2048
#define RPB   32              // rows per block
#define NW    16              // waves per block (1024 threads)
#define SCW   256             // super-chunk width in d (floats per row per buffer)
#define NSC   (DCOLS / SCW)   // 8 super-chunks
#define TILEF (RPB * SCW)     // 8192 floats = 32 KB per buffer
#define PSTR  15              // partials row stride

__global__ __launch_bounds__(1024)
void ped_det_kernel(const float* __restrict__ feat,
                    const float* __restrict__ Wb,   // [2048][12]
                    const float* __restrict__ bb,   // [12]
                    const float* __restrict__ Wc,   // [2048][3]
                    const float* __restrict__ bc,   // [3]
                    float* __restrict__ out,
                    int nrows)
{
    __shared__ __align__(16) float lds[2][TILEF];   // 65,536 B total
    float* P = &lds[0][0];   // [16][32][15] partials (30,720 B) alias, after loop
    float* S = P;            // [32][16] biased sums alias, behind further barrier

    const int t    = threadIdx.x;
    const int lane = t & 63;
    const int w    = t >> 6;
    const int wu   = __builtin_amdgcn_readfirstlane(w);  // wave-uniform -> scalar W
    const int row  = lane & 31;          // compute row (0..31), shared by half-waves
    const int half = lane >> 5;          // 0: j=0..7, 1: j=8..14

    const int rowBase = blockIdx.x * RPB;
    const float* fbase = feat + (size_t)rowBase * DCOLS;

    // --- staging: wave wu stages rows {wu*2, wu*2+1}; one instruction = one
    // full 1KB row-span. Dest slot = lane (linear, 16B units); source slot =
    // lane ^ (r&7) (XOR within 128B groups -> same 16-line set, coalescing
    // preserved; gives conflict-reduced swizzled ds_read later, rule 21).
    auto STAGE = [&](int sc, int p) {
#pragma unroll
        for (int i = 0; i < 2; ++i) {
            const int r = wu * 2 + i;
            const float* g = fbase + (size_t)r * DCOLS + sc * SCW
                           + ((lane ^ (r & 7)) << 2);
            const float* l = &lds[p][r * SCW];               // wave-uniform base
            __builtin_amdgcn_global_load_lds(
                (const __attribute__((address_space(1))) void*)g,
                (__attribute__((address_space(3))) void*)l, 16, 0, 0);
        }
    };

    float acc[8];
#pragma unroll
    for (int j = 0; j < 8; ++j) acc[j] = 0.0f;

    STAGE(0, 0);

    for (int sc = 0; sc < NSC; ++sc) {
        if (sc + 1 < NSC) {
            STAGE(sc + 1, (sc + 1) & 1);
            asm volatile("s_waitcnt vmcnt(2)" ::: "memory");  // retire stage sc only
        } else {
            asm volatile("s_waitcnt vmcnt(0)" ::: "memory");
        }
        asm volatile("s_barrier" ::: "memory");   // buffer sc&1 fully resident

        const float* buf = &lds[sc & 1][0];
        // wave wu consumes d-slice [wu*16, wu*16+16) of this 256-wide buffer,
        // as 4 float4 reads at content slots s = wu*4+q (wave-uniform).
        if (half == 0) {
#pragma unroll
            for (int q = 0; q < 4; ++q) {
                const int s = wu * 4 + q;
                const float4 f = *(const float4*)(buf + row * SCW
                                                  + ((s ^ (row & 7)) << 2));
                const int du = sc * SCW + wu * 16 + q * 4;
                const float* __restrict__ wbp = Wb + (size_t)du * 12;
                const float fv[4] = { f.x, f.y, f.z, f.w };
#pragma unroll
                for (int jj = 0; jj < 4; ++jj) {
                    const float v = fv[jj];
                    acc[0] += v * wbp[jj * 12 + 0];
                    acc[1] += v * wbp[jj * 12 + 1];
                    acc[2] += v * wbp[jj * 12 + 2];
                    acc[3] += v * wbp[jj * 12 + 3];
                    acc[4] += v * wbp[jj * 12 + 4];
                    acc[5] += v * wbp[jj * 12 + 5];
                    acc[6] += v * wbp[jj * 12 + 6];
                    acc[7] += v * wbp[jj * 12 + 7];
                }
            }
        } else {
#pragma unroll
            for (int q = 0; q < 4; ++q) {
                const int s = wu * 4 + q;
                const float4 f = *(const float4*)(buf + row * SCW
                                                  + ((s ^ (row & 7)) << 2));
                const int du = sc * SCW + wu * 16 + q * 4;
                const float* __restrict__ wbp = Wb + (size_t)du * 12;
                const float* __restrict__ wcp = Wc + (size_t)du * 3;
                const float fv[4] = { f.x, f.y, f.z, f.w };
#pragma unroll
                for (int jj = 0; jj < 4; ++jj) {
                    const float v = fv[jj];
                    acc[0] += v * wbp[jj * 12 + 8];
                    acc[1] += v * wbp[jj * 12 + 9];
                    acc[2] += v * wbp[jj * 12 + 10];
                    acc[3] += v * wbp[jj * 12 + 11];
                    acc[4] += v * wcp[jj * 3 + 0];
                    acc[5] += v * wcp[jj * 3 + 1];
                    acc[6] += v * wcp[jj * 3 + 2];
                }
            }
        }

        // reads must be in registers before this buffer is restaged next iter
        asm volatile("s_waitcnt lgkmcnt(0)" ::: "memory");
        asm volatile("s_barrier" ::: "memory");
    }

    // ---- write per-wave partials: [wave][row][15], halves write disjoint j
    {
        float* pp = &P[(wu * RPB + row) * PSTR + half * 8];
        if (half == 0) {
#pragma unroll
            for (int j = 0; j < 8; ++j) pp[j] = acc[j];
        } else {
#pragma unroll
            for (int j = 0; j < 7; ++j) pp[j] = acc[j];
        }
    }
    __syncthreads();

    // ---- reduce 16 wave-partials per (row, j), add bias
    float sval = 0.0f;
    int rl = 0, jj = 0;
    if (t < RPB * 15) {                 // 480 items, t = rl*15 + jj
        rl = t / 15;
        jj = t - rl * 15;
        float s = 0.0f;
#pragma unroll
        for (int w2 = 0; w2 < NW; ++w2)
            s += P[(w2 * RPB + rl) * PSTR + jj];
        s += (jj < 12) ? bb[jj] : bc[jj - 12];
        sval = s;
    }
    __syncthreads();                    // all P reads done before S (alias) written

    if (t < RPB * 15)
        S[rl * 16 + jj] = sval;
    __syncthreads();

    // ---- epilogue: sigmoid, stable top-3 (ties -> lower index), threshold, store
    if (t < RPB) {
        const int r2 = t;
        float box[12];
#pragma unroll
        for (int j = 0; j < 12; ++j) box[j] = S[r2 * 16 + j];
        float conf[3];
#pragma unroll
        for (int a = 0; a < 3; ++a)
            conf[a] = 1.0f / (1.0f + __expf(-S[r2 * 16 + 12 + a]));

        int i0 = 0; float m0 = conf[0];
        if (conf[1] > m0) { i0 = 1; m0 = conf[1]; }
        if (conf[2] > m0) { i0 = 2; m0 = conf[2]; }
        const int ra = (i0 == 0) ? 1 : 0;
        const int rb = (i0 == 2) ? 1 : 2;
        int i1, i2;
        if (conf[rb] > conf[ra]) { i1 = rb; i2 = ra; }
        else                     { i1 = ra; i2 = rb; }
        const int idx[3] = { i0, i1, i2 };

        const int ro = blockIdx.x * RPB + r2;
        float* boxout  = out + (size_t)ro * 12;
        float* confout = out + (size_t)nrows * 12 + (size_t)ro * 3;
        float* valout  = out + (size_t)nrows * 15 + (size_t)ro * 3;
#pragma unroll
        for (int sl = 0; sl < 3; ++sl) {
            const int   a   = idx[sl];
            const float cv  = conf[a];
            const bool  vld = cv > 0.5f;
            float4 bx;
            bx.x = vld ? box[a * 4 + 0] : 0.0f;
            bx.y = vld ? box[a * 4 + 1] : 0.0f;
            bx.z = vld ? box[a * 4 + 2] : 0.0f;
            bx.w = vld ? box[a * 4 + 3] : 0.0f;
            *(float4*)(boxout + sl * 4) = bx;
            confout[sl] = cv;
            valout[sl]  = vld ? 1.0f : 0.0f;
        }
    }
}

extern "C" void kernel_launch(void* const* d_in, const int* in_sizes, int n_in,
                              void* d_out, int out_size, void* d_ws, size_t ws_size,
                              hipStream_t stream) {
    const float* feat = (const float*)d_in[0];
    const float* Wb   = (const float*)d_in[1];
    const float* bb   = (const float*)d_in[2];
    const float* Wc   = (const float*)d_in[3];
    const float* bc   = (const float*)d_in[4];
    float* out = (float*)d_out;

    const int nrows   = in_sizes[0] / DCOLS;   // 16384
    const int nblocks = nrows / RPB;           // 512 -> 2 blocks/CU, 32 waves/CU

    ped_det_kernel<<<dim3(nblocks), dim3(1024), 0, stream>>>(
        feat, Wb, bb, Wc, bc, out, nrows);
}